// Round 7
// baseline (346.186 us; speedup 1.0000x reference)
//
#include <hip/hip_runtime.h>
#include <cmath>

// ---------------------------------------------------------------------------
// Decoder_1898375544952: STGCN decoder (radix CSR + u8-quant gather + MFMA)
//   h0 = x @ W_lin + b_lin                         [N,16]
//   h3 = relu(h0 @ Ws3 + mean_agg(h0) @ Wn3 + b3)  [N,32]
//   h2 = relu(h3 @ Ws2 + mean_agg(h3) @ Wn2 + b2)  [N,64]
//   out= sigm(h2 @ Ws1 + mean_agg(h2) @ Wn1 + b1)  [N,128]
//
// History: R11 8-wide fp16 gather 336.7. R12 chunking 379. R13 phase-sort
//   343. R14 u8 quant (+NT poisons) 354. R15 fused gather+GEMM 374 (LDS ->
//   26% occ). R16 partition pack-u32 + NBLK 256 + merged wt: 317.1 (BEST);
//   partition WRITE fix delivered ~20us as predicted; gather<64> control
//   unchanged (65us / 213MB FETCH).
// R17: graft R14's proven piece onto R16: u8 global-scale quant tables for
//   the h3/h2 gathers (relu outputs >= 0; exact int accumulation; global
//   max via GEMM-epilogue TRACKMAX). NO NT stores/loads anywhere new (that
//   was R14's regression: NT agg bypassed L2 and the GEMMs re-fetched from
//   HBM). Layer-3 gather + CSR build + GEMM bodies identical to R16.
//   R14 evidence: absmax unchanged => quant noise below fp16 error floor.
// ---------------------------------------------------------------------------

typedef __attribute__((ext_vector_type(8))) _Float16 half8;
typedef __attribute__((ext_vector_type(4))) float floatx4;

#define NBUCKET 512
#define BUCKET_SHIFT 8   // 256 nodes per bucket; N = 131072 = 512*256

// ---- init: zero the two scale slots (float-as-int, values >= 0) ----
__global__ void init_scales_kernel(int* __restrict__ g) { g[0] = 0; g[1] = 0; }

// ---- Pass A: per-block bucket histogram (LDS atomics only) ----
__global__ __launch_bounds__(256) void bucket_hist_kernel(
    const int* __restrict__ dst, int* __restrict__ bcnt, int E, int EPB, int nblk) {
    __shared__ int lh[NBUCKET];
    for (int i = threadIdx.x; i < NBUCKET; i += 256) lh[i] = 0;
    __syncthreads();
    int base = blockIdx.x * EPB;
    int end  = min(base + EPB, E);
    for (int i = base + threadIdx.x; i < end; i += 256)
        atomicAdd(&lh[dst[i] >> BUCKET_SHIFT], 1);
    __syncthreads();
    for (int i = threadIdx.x; i < NBUCKET; i += 256)
        bcnt[i * nblk + blockIdx.x] = lh[i];        // bucket-major
}

// ---- scan helpers ----
__global__ void scan1_kernel(const int* __restrict__ in, int* __restrict__ out,
                             int* __restrict__ bsum) {
    __shared__ int s[256];
    int i = blockIdx.x * 256 + threadIdx.x;
    int v = in[i];
    s[threadIdx.x] = v;
    __syncthreads();
    for (int off = 1; off < 256; off <<= 1) {
        int t = (threadIdx.x >= off) ? s[threadIdx.x - off] : 0;
        __syncthreads();
        s[threadIdx.x] += t;
        __syncthreads();
    }
    out[i] = s[threadIdx.x] - v;
    if (threadIdx.x == 255) bsum[blockIdx.x] = s[255];
}

__global__ void scan2_kernel(int* __restrict__ bsum, int NB) {
    extern __shared__ int s2[];
    int v = (threadIdx.x < NB) ? bsum[threadIdx.x] : 0;
    s2[threadIdx.x] = v;
    __syncthreads();
    for (int off = 1; off < NB; off <<= 1) {
        int t = (threadIdx.x >= off) ? s2[threadIdx.x - off] : 0;
        __syncthreads();
        s2[threadIdx.x] += t;
        __syncthreads();
    }
    if (threadIdx.x < NB) bsum[threadIdx.x] = s2[threadIdx.x] - v;
}

__global__ void scan3_kernel(int* __restrict__ out, const int* __restrict__ bsum) {
    int i = blockIdx.x * 256 + threadIdx.x;
    out[i] += bsum[blockIdx.x];
}

// ---- Pass C: partition edges into bucket segments (LDS cursors) ----
// Packed entry: (src << 8) | (dst & 255). src < 2^24, bucket-local dst 8b.
__global__ __launch_bounds__(256) void partition_kernel(
    const int* __restrict__ src, const int* __restrict__ dst,
    const int* __restrict__ bofs, int* __restrict__ part,
    int E, int EPB, int nblk) {
    __shared__ int cur[NBUCKET];
    for (int i = threadIdx.x; i < NBUCKET; i += 256)
        cur[i] = bofs[i * nblk + blockIdx.x];
    __syncthreads();
    int base = blockIdx.x * EPB;
    int end  = min(base + EPB, E);
    for (int i = base + threadIdx.x; i < end; i += 256) {
        int d = dst[i];
        int p = atomicAdd(&cur[d >> BUCKET_SHIFT], 1);
        part[p] = (src[i] << 8) | (d & 255);
    }
}

// ---- Pass D: per-bucket local CSR (row_ptr + csr_src), all LDS-local ----
__global__ __launch_bounds__(256) void local_csr_kernel(
    const int* __restrict__ bofs, const int* __restrict__ part,
    int* __restrict__ row_ptr, int* __restrict__ csr_src,
    int N, int E, int nblk) {
    __shared__ int cnt[256];
    __shared__ int offs[256];
    const int u      = blockIdx.x;
    const int node0  = u << BUCKET_SHIFT;
    const int bstart = bofs[(size_t)u * nblk];
    const int bend   = (u + 1 < gridDim.x) ? bofs[(size_t)(u + 1) * nblk] : E;

    cnt[threadIdx.x] = 0;
    __syncthreads();
    for (int i = bstart + threadIdx.x; i < bend; i += 256)
        atomicAdd(&cnt[part[i] & 255], 1);
    __syncthreads();

    int v = cnt[threadIdx.x];
    offs[threadIdx.x] = v;
    __syncthreads();
    for (int off = 1; off < 256; off <<= 1) {
        int t = (threadIdx.x >= off) ? offs[threadIdx.x - off] : 0;
        __syncthreads();
        offs[threadIdx.x] += t;
        __syncthreads();
    }
    int excl = offs[threadIdx.x] - v;
    int rbase = bstart + excl;
    if (node0 + threadIdx.x < N) row_ptr[node0 + threadIdx.x] = rbase;
    if (u == 0 && threadIdx.x == 0) row_ptr[N] = E;
    __syncthreads();
    cnt[threadIdx.x] = rbase;       // reuse as cursor
    __syncthreads();
    for (int i = bstart + threadIdx.x; i < bend; i += 256) {
        int e = part[i];
        int p = atomicAdd(&cnt[e & 255], 1);
        csr_src[p] = e >> 8;
    }
}

// ---- merged weight transpose+concat for all 3 layers (1 launch) ----
// Wt[n][k] = (k<CI ? Ws[k][n] : Wn[k-CI][n]) as fp16.
__global__ void wt_all_kernel(
    const float* __restrict__ Ws1, const float* __restrict__ Wn1, _Float16* __restrict__ Wt1,
    const float* __restrict__ Ws2, const float* __restrict__ Wn2, _Float16* __restrict__ Wt2,
    const float* __restrict__ Ws3, const float* __restrict__ Wn3, _Float16* __restrict__ Wt3) {
    int idx = blockIdx.x * 256 + threadIdx.x;
    const float *Ws, *Wn; _Float16* Wt; int CI, NOUT;
    if (idx < 16384)        { Ws = Ws1; Wn = Wn1; Wt = Wt1; CI = 64; NOUT = 128; }
    else if (idx < 20480)   { idx -= 16384; Ws = Ws2; Wn = Wn2; Wt = Wt2; CI = 32; NOUT = 64; }
    else if (idx < 21504)   { idx -= 20480; Ws = Ws3; Wn = Wn3; Wt = Wt3; CI = 16; NOUT = 32; }
    else return;
    int K = 2 * CI;
    int n = idx / K, k = idx - n * K;
    float v = (k < CI) ? Ws[(size_t)k * NOUT + n] : Wn[(size_t)(k - CI) * NOUT + n];
    Wt[n * K + k] = (_Float16)v;
}

// h0 = x @ W (16x16) + b, stored fp16
__global__ void lin16_kernel(const float* __restrict__ x, const float* __restrict__ W,
                             const float* __restrict__ b, _Float16* __restrict__ h, int N) {
    __shared__ float sW[256];
    __shared__ float sb[16];
    sW[threadIdx.x] = W[threadIdx.x];          // blockDim.x == 256
    if (threadIdx.x < 16) sb[threadIdx.x] = b[threadIdx.x];
    __syncthreads();
    int n = blockIdx.x * blockDim.x + threadIdx.x;
    if (n >= N) return;
    const float4* xr = (const float4*)(x + (size_t)n * 16);
    float4 x0 = xr[0], x1 = xr[1], x2 = xr[2], x3 = xr[3];
    float xi[16] = {x0.x, x0.y, x0.z, x0.w, x1.x, x1.y, x1.z, x1.w,
                    x2.x, x2.y, x2.z, x2.w, x3.x, x3.y, x3.z, x3.w};
    float o[16];
#pragma unroll
    for (int j = 0; j < 16; j++) o[j] = sb[j];
#pragma unroll
    for (int k = 0; k < 16; k++) {
        float xv = xi[k];
#pragma unroll
        for (int j = 0; j < 16; j++) o[j] += xv * sW[k * 16 + j];
    }
    half8 h0v, h1v;
#pragma unroll
    for (int j = 0; j < 8; j++) { h0v[j] = (_Float16)o[j]; h1v[j] = (_Float16)o[j + 8]; }
    half8* hr = (half8*)(h + (size_t)n * 16);
    hr[0] = h0v;
    hr[1] = h1v;
}

// agg[n][g*8..] = (1/max(deg,1)) * sum over CSR neighbors of h[src][g*8..]
// R11 form: 8-wide unrolled rounds + single masked tail round. (layer 3)
template <int C>
__global__ __launch_bounds__(256) void gather_kernel(
    const int* __restrict__ row_ptr, const int* __restrict__ csr_src,
    const _Float16* __restrict__ h, _Float16* __restrict__ agg, int N) {
    constexpr int GP = C / 8;
    int t = blockIdx.x * blockDim.x + threadIdx.x;
    int total = N * GP;
    if (t >= total) return;
    int n = t / GP;
    int g = t - n * GP;
    const int beg = row_ptr[n];
    const int end = row_ptr[n + 1];
    const size_t goff = (size_t)g * 8;

    float a0[8], a1[8];
#pragma unroll
    for (int i = 0; i < 8; i++) { a0[i] = 0.f; a1[i] = 0.f; }

    int j = beg;
    for (; j + 8 <= end; j += 8) {
        int i0 = csr_src[j + 0], i1 = csr_src[j + 1], i2 = csr_src[j + 2], i3 = csr_src[j + 3];
        int i4 = csr_src[j + 4], i5 = csr_src[j + 5], i6 = csr_src[j + 6], i7 = csr_src[j + 7];
        half8 v0 = *(const half8*)(h + (size_t)i0 * C + goff);
        half8 v1 = *(const half8*)(h + (size_t)i1 * C + goff);
        half8 v2 = *(const half8*)(h + (size_t)i2 * C + goff);
        half8 v3 = *(const half8*)(h + (size_t)i3 * C + goff);
        half8 v4 = *(const half8*)(h + (size_t)i4 * C + goff);
        half8 v5 = *(const half8*)(h + (size_t)i5 * C + goff);
        half8 v6 = *(const half8*)(h + (size_t)i6 * C + goff);
        half8 v7 = *(const half8*)(h + (size_t)i7 * C + goff);
#pragma unroll
        for (int i = 0; i < 8; i++) {
            a0[i] += ((float)v0[i] + (float)v2[i]) + ((float)v4[i] + (float)v6[i]);
            a1[i] += ((float)v1[i] + (float)v3[i]) + ((float)v5[i] + (float)v7[i]);
        }
    }
    if (j < end) {
        const int last = end - 1;
        int i0 = csr_src[j];
        int i1 = csr_src[min(j + 1, last)];
        int i2 = csr_src[min(j + 2, last)];
        int i3 = csr_src[min(j + 3, last)];
        int i4 = csr_src[min(j + 4, last)];
        int i5 = csr_src[min(j + 5, last)];
        int i6 = csr_src[min(j + 6, last)];
        int i7 = csr_src[min(j + 7, last)];
        half8 v0 = *(const half8*)(h + (size_t)i0 * C + goff);
        half8 v1 = *(const half8*)(h + (size_t)i1 * C + goff);
        half8 v2 = *(const half8*)(h + (size_t)i2 * C + goff);
        half8 v3 = *(const half8*)(h + (size_t)i3 * C + goff);
        half8 v4 = *(const half8*)(h + (size_t)i4 * C + goff);
        half8 v5 = *(const half8*)(h + (size_t)i5 * C + goff);
        half8 v6 = *(const half8*)(h + (size_t)i6 * C + goff);
        half8 v7 = *(const half8*)(h + (size_t)i7 * C + goff);
        float w1 = (j + 1 < end) ? 1.f : 0.f;
        float w2 = (j + 2 < end) ? 1.f : 0.f;
        float w3 = (j + 3 < end) ? 1.f : 0.f;
        float w4 = (j + 4 < end) ? 1.f : 0.f;
        float w5 = (j + 5 < end) ? 1.f : 0.f;
        float w6 = (j + 6 < end) ? 1.f : 0.f;
        float w7 = (j + 7 < end) ? 1.f : 0.f;
#pragma unroll
        for (int i = 0; i < 8; i++) {
            a0[i] += ((float)v0[i] + w2 * (float)v2[i]) + (w4 * (float)v4[i] + w6 * (float)v6[i]);
            a1[i] += (w1 * (float)v1[i] + w3 * (float)v3[i]) + (w5 * (float)v5[i] + w7 * (float)v7[i]);
        }
    }

    float inv = 1.0f / fmaxf((float)(end - beg), 1.0f);
    half8 r;
#pragma unroll
    for (int i = 0; i < 8; i++) r[i] = (_Float16)((a0[i] + a1[i]) * inv);
    *(half8*)(agg + (size_t)n * C + goff) = r;
}

// ---- quantize: q[i] = round(h[i] * 255/M), h >= 0 (relu) ----
__global__ __launch_bounds__(256) void quant_kernel(
    const _Float16* __restrict__ h, const int* __restrict__ maxbits,
    unsigned char* __restrict__ q, int total16) {
    int t = blockIdx.x * 256 + threadIdx.x;
    if (t >= total16) return;
    float M = __int_as_float(*maxbits);
    float inv = (M > 1e-20f) ? 255.0f / M : 0.0f;
    const half8* hp = (const half8*)(h + (size_t)t * 16);
    half8 v0 = hp[0], v1 = hp[1];
    unsigned int dw[4] = {0u, 0u, 0u, 0u};
#pragma unroll
    for (int i = 0; i < 8; i++) {
        unsigned int b = (unsigned int)((float)v0[i] * inv + 0.5f);
        if (b > 255u) b = 255u;
        dw[i >> 2] |= b << ((i & 3) * 8);
    }
#pragma unroll
    for (int i = 0; i < 8; i++) {
        unsigned int b = (unsigned int)((float)v1[i] * inv + 0.5f);
        if (b > 255u) b = 255u;
        dw[2 + (i >> 2)] |= b << ((i & 3) * 8);
    }
    uint4 o; o.x = dw[0]; o.y = dw[1]; o.z = dw[2]; o.w = dw[3];
    *(uint4*)(q + (size_t)t * 16) = o;
}

// int-accumulate helpers for u8 gather (exact: sum <= 255*deg << 2^31)
#define ACC4(d, o)                                 \
    { unsigned int _d = (d);                        \
      a[(o)]     += _d & 0xffu;                     \
      a[(o) + 1] += (_d >> 8) & 0xffu;              \
      a[(o) + 2] += (_d >> 16) & 0xffu;             \
      a[(o) + 3] += _d >> 24; }
#define ACC4W(d, w, o)                              \
    { unsigned int _d = (d); int _w = (w);          \
      a[(o)]     += _w * (int)(_d & 0xffu);         \
      a[(o) + 1] += _w * (int)((_d >> 8) & 0xffu);  \
      a[(o) + 2] += _w * (int)((_d >> 16) & 0xffu); \
      a[(o) + 3] += _w * (int)(_d >> 24); }

// ---- quantized gather: agg[n][g*16..] = (M/255/deg) * int-sum of q rows ----
// Row = C bytes; GP = C/16 lanes/node, each lane one contiguous uint4 (16B).
// Normal cached loads/stores (R14's NT variants were the regression).
template <int C>
__global__ __launch_bounds__(256) void gatherq_kernel(
    const int* __restrict__ row_ptr, const int* __restrict__ csr_src,
    const unsigned char* __restrict__ hq, const int* __restrict__ maxbits,
    _Float16* __restrict__ agg, int N) {
    constexpr int GP = C / 16;
    int t = blockIdx.x * 256 + threadIdx.x;
    if (t >= N * GP) return;
    int n = t / GP;
    int g = t & (GP - 1);
    const int beg = row_ptr[n];
    const int end = row_ptr[n + 1];
    const size_t goff = (size_t)g * 16;

    int a[16];
#pragma unroll
    for (int i = 0; i < 16; i++) a[i] = 0;

    int j = beg;
    for (; j + 4 <= end; j += 4) {
        int i0 = csr_src[j + 0], i1 = csr_src[j + 1];
        int i2 = csr_src[j + 2], i3 = csr_src[j + 3];
        uint4 q0 = *(const uint4*)(hq + (size_t)i0 * C + goff);
        uint4 q1 = *(const uint4*)(hq + (size_t)i1 * C + goff);
        uint4 q2 = *(const uint4*)(hq + (size_t)i2 * C + goff);
        uint4 q3 = *(const uint4*)(hq + (size_t)i3 * C + goff);
        ACC4(q0.x, 0) ACC4(q0.y, 4) ACC4(q0.z, 8) ACC4(q0.w, 12)
        ACC4(q1.x, 0) ACC4(q1.y, 4) ACC4(q1.z, 8) ACC4(q1.w, 12)
        ACC4(q2.x, 0) ACC4(q2.y, 4) ACC4(q2.z, 8) ACC4(q2.w, 12)
        ACC4(q3.x, 0) ACC4(q3.y, 4) ACC4(q3.z, 8) ACC4(q3.w, 12)
    }
    if (j < end) {
        const int last = end - 1;
        int i0 = csr_src[j];
        int i1 = csr_src[min(j + 1, last)];
        int i2 = csr_src[min(j + 2, last)];
        int i3 = csr_src[min(j + 3, last)];
        uint4 q0 = *(const uint4*)(hq + (size_t)i0 * C + goff);
        uint4 q1 = *(const uint4*)(hq + (size_t)i1 * C + goff);
        uint4 q2 = *(const uint4*)(hq + (size_t)i2 * C + goff);
        uint4 q3 = *(const uint4*)(hq + (size_t)i3 * C + goff);
        int w1 = (j + 1 < end) ? 1 : 0;
        int w2 = (j + 2 < end) ? 1 : 0;
        int w3 = (j + 3 < end) ? 1 : 0;
        ACC4(q0.x, 0) ACC4(q0.y, 4) ACC4(q0.z, 8) ACC4(q0.w, 12)
        ACC4W(q1.x, w1, 0) ACC4W(q1.y, w1, 4) ACC4W(q1.z, w1, 8) ACC4W(q1.w, w1, 12)
        ACC4W(q2.x, w2, 0) ACC4W(q2.y, w2, 4) ACC4W(q2.z, w2, 8) ACC4W(q2.w, w2, 12)
        ACC4W(q3.x, w3, 0) ACC4W(q3.y, w3, 4) ACC4W(q3.z, w3, 8) ACC4W(q3.w, w3, 12)
    }

    float M = __int_as_float(*maxbits);
    float sc = (M * (1.0f / 255.0f)) / fmaxf((float)(end - beg), 1.0f);
    half8 rl, rh;
#pragma unroll
    for (int i = 0; i < 8; i++) {
        rl[i] = (_Float16)((float)a[i] * sc);
        rh[i] = (_Float16)((float)a[i + 8] * sc);
    }
    half8* ap = (half8*)(agg + (size_t)n * C + goff);
    ap[0] = rl;
    ap[1] = rh;
}

// ---- MFMA GEMM: out = act([h | a] @ Wt^T + b) with Wt[n][K] fp16 ----
// TRACKMAX (relu layers): global output max -> maxbits (LDS + atomicMax on
// float bits; valid since relu output >= 0).
template <int CI, int NOUT, int ACT, bool OUT_F16, bool TRACKMAX>
__global__ __launch_bounds__(256) void mfma_gemm_kernel(
    const _Float16* __restrict__ hbuf, const _Float16* __restrict__ abuf,
    const _Float16* __restrict__ Wt,   // [NOUT][K] fp16
    const float* __restrict__ bias, void* __restrict__ outp,
    int* __restrict__ maxbits, int N)
{
    constexpr int K   = 2 * CI;
    constexpr int KS  = K / 32;        // k-steps (4/2/1)
    constexpr int CT  = NOUT / 16;     // col tiles (8/4/2)
    constexpr int LDW = K + 8;         // padded LDS row (halves)
    __shared__ _Float16 Bt[NOUT * LDW];
    __shared__ int smax;

    const int tid = threadIdx.x;
    for (int idx = tid; idx < NOUT * (K / 8); idx += 256) {
        int n  = idx / (K / 8);
        int kq = idx - n * (K / 8);
        *(half8*)&Bt[n * LDW + kq * 8] = *(const half8*)(Wt + (size_t)n * K + kq * 8);
    }
    if (TRACKMAX && tid == 0) smax = 0;
    __syncthreads();

    const int wave = tid >> 6;
    const int lane = tid & 63;
    const int m    = lane & 15;
    const int quad = lane >> 4;
    const int row0 = blockIdx.x * 64 + wave * 16;
    const size_t row = (size_t)(row0 + m);

    floatx4 acc[CT];
#pragma unroll
    for (int c = 0; c < CT; c++) acc[c] = (floatx4){0.f, 0.f, 0.f, 0.f};

#pragma unroll
    for (int s = 0; s < KS; s++) {
        int k8 = s * 32 + quad * 8;
        const _Float16* Ap = (k8 < CI) ? (hbuf + row * CI + k8)
                                       : (abuf + row * CI + (k8 - CI));
        half8 a = *(const half8*)Ap;
#pragma unroll
        for (int c = 0; c < CT; c++) {
            half8 b = *(const half8*)&Bt[(c * 16 + m) * LDW + k8];
            acc[c] = __builtin_amdgcn_mfma_f32_16x16x32_f16(a, b, acc[c], 0, 0, 0);
        }
    }

    float tmax = 0.0f;
#pragma unroll
    for (int c = 0; c < CT; c++) {
        int col = c * 16 + m;
        float bv = bias[col];
#pragma unroll
        for (int j = 0; j < 4; j++) {
            int orow = row0 + quad * 4 + j;
            float v = acc[c][j] + bv;
            if (ACT == 0) v = fmaxf(v, 0.0f);
            else          v = 1.0f / (1.0f + __expf(-v));
            if (TRACKMAX) tmax = fmaxf(tmax, v);
            if (OUT_F16) ((_Float16*)outp)[(size_t)orow * NOUT + col] = (_Float16)v;
            else         ((float*)outp)[(size_t)orow * NOUT + col] = v;
        }
    }
    if (TRACKMAX) {
        atomicMax(&smax, __float_as_int(tmax));
        __syncthreads();
        if (tid == 0) atomicMax(maxbits, smax);
    }
}

extern "C" void kernel_launch(void* const* d_in, const int* in_sizes, int n_in,
                              void* d_out, int out_size, void* d_ws, size_t ws_size,
                              hipStream_t stream) {
    const float* x     = (const float*)d_in[0];
    const int*   ei    = (const int*)d_in[1];
    // d_in[2]: batch (unused)
    const float* W_lin = (const float*)d_in[3];
    const float* b_lin = (const float*)d_in[4];
    const float* Ws3   = (const float*)d_in[5];
    const float* Wn3   = (const float*)d_in[6];
    const float* b3    = (const float*)d_in[7];
    const float* Ws2   = (const float*)d_in[8];
    const float* Wn2   = (const float*)d_in[9];
    const float* b2    = (const float*)d_in[10];
    const float* Ws1   = (const float*)d_in[11];
    const float* Wn1   = (const float*)d_in[12];
    const float* b1    = (const float*)d_in[13];
    float* out = (float*)d_out;

    const int N = in_sizes[0] / 16;
    const int E = in_sizes[1] / 2;
    const int* src = ei;
    const int* dst = ei + E;

    const int NBLK = 256;                       // partition blocks (~64B runs)
    const int EPB  = (E + NBLK - 1) / NBLK;
    const int M    = NBUCKET * NBLK;            // 131072 count entries
    const int NB2  = M / 256;                   // 512

    // Workspace (ints unless noted).
    int* wsi = (int*)d_ws;
    int* row_ptr = wsi;
    size_t B0 = ((size_t)(N + 1) + 3) & ~(size_t)3;
    int* bcnt = wsi + B0;
    int* bofs = bcnt + M;
    int* bsum = bofs + M;
    int* gmax = bsum + NB2;                     // [0]=max(h3), [1]=max(h2)
    size_t C0 = (B0 + 2 * (size_t)M + (size_t)NB2 + 2 + 3) & ~(size_t)3;
    int* csr_src = wsi + C0;
    size_t P0 = (C0 + (size_t)E + 3) & ~(size_t)3;
    int* part = wsi + P0;                       // E packed u32; 2E reserved
    size_t H0 = (P0 + 2 * (size_t)E + 3) & ~(size_t)3;
    _Float16* regA = (_Float16*)(wsi + H0);
    _Float16* regB = regA + (size_t)64 * N;
    _Float16* Wt1  = regB + (size_t)64 * N;     // 128*128 = 16384 halves
    _Float16* Wt2  = Wt1 + 16384;               // 64*64   = 4096
    _Float16* Wt3  = Wt2 + 4096;                // 32*32   = 1024

    _Float16* h0    = regA;
    _Float16* agg16 = regA + (size_t)16 * N;
    _Float16* h2    = regA;                    // after h0/agg16 dead
    _Float16* h3    = regB;
    _Float16* agg32 = regB + (size_t)32 * N;
    _Float16* agg64 = regB;                    // after h3/agg32 dead

    // quantized tables overlay part's 2E-int reservation (part dead by then)
    unsigned char* h3q = (unsigned char*)part;                   // N*32 B
    unsigned char* h2q = (unsigned char*)part + (size_t)32 * N;  // N*64 B

    const int BLK = 256;

    // ---- init scale slots ----
    init_scales_kernel<<<1, 1, 0, stream>>>(gmax);

    // ---- weight transposes (1 merged launch) ----
    wt_all_kernel<<<(21504 + 255) / 256, 256, 0, stream>>>(
        Ws1, Wn1, Wt1, Ws2, Wn2, Wt2, Ws3, Wn3, Wt3);

    // ---- radix CSR build: zero global atomics ----
    bucket_hist_kernel<<<NBLK, 256, 0, stream>>>(dst, bcnt, E, EPB, NBLK);
    scan1_kernel<<<NB2, 256, 0, stream>>>(bcnt, bofs, bsum);
    scan2_kernel<<<1, NB2, NB2 * sizeof(int), stream>>>(bsum, NB2);
    scan3_kernel<<<NB2, 256, 0, stream>>>(bofs, bsum);
    partition_kernel<<<NBLK, 256, 0, stream>>>(src, dst, bofs, part, E, EPB, NBLK);
    local_csr_kernel<<<NBUCKET, 256, 0, stream>>>(bofs, part, row_ptr, csr_src, N, E, NBLK);

    // ---- h0 = x @ W_lin + b_lin (fp16 out) ----
    lin16_kernel<<<(N + BLK - 1) / BLK, BLK, 0, stream>>>(x, W_lin, b_lin, h0, N);

    // ---- block3: 16 -> 32, relu (fp16 gather; h0 may be negative) ----
    gather_kernel<16><<<((size_t)N * 2 + BLK - 1) / BLK, BLK, 0, stream>>>(row_ptr, csr_src, h0, agg16, N);
    mfma_gemm_kernel<16, 32, 0, true, true><<<N / 64, 256, 0, stream>>>(
        h0, agg16, Wt3, b3, h3, gmax + 0, N);

    // ---- block2: 32 -> 64, relu (u8 quant gather) ----
    quant_kernel<<<(N * 2 + BLK - 1) / BLK, BLK, 0, stream>>>(h3, gmax + 0, h3q, N * 2);
    gatherq_kernel<32><<<((size_t)N * 2 + BLK - 1) / BLK, BLK, 0, stream>>>(
        row_ptr, csr_src, h3q, gmax + 0, agg32, N);
    mfma_gemm_kernel<32, 64, 0, true, true><<<N / 64, 256, 0, stream>>>(
        h3, agg32, Wt2, b2, h2, gmax + 1, N);

    // ---- block1: 64 -> 128, sigmoid -> d_out fp32 (u8 quant gather) ----
    quant_kernel<<<(N * 4 + BLK - 1) / BLK, BLK, 0, stream>>>(h2, gmax + 1, h2q, N * 4);
    gatherq_kernel<64><<<((size_t)N * 4 + BLK - 1) / BLK, BLK, 0, stream>>>(
        row_ptr, csr_src, h2q, gmax + 1, agg64, N);
    mfma_gemm_kernel<64, 128, 1, false, false><<<N / 64, 256, 0, stream>>>(
        h2, agg64, Wt1, b1, out, nullptr, N);
}

// Round 8
// 324.315 us; speedup vs baseline: 1.0674x; 1.0674x over previous
//
#include <hip/hip_runtime.h>
#include <cmath>

// ---------------------------------------------------------------------------
// Decoder_1898375544952: STGCN decoder (radix CSR + layer1 u8 gather + MFMA)
//   h0 = x @ W_lin + b_lin                         [N,16]
//   h3 = relu(h0 @ Ws3 + mean_agg(h0) @ Wn3 + b3)  [N,32]
//   h2 = relu(h3 @ Ws2 + mean_agg(h3) @ Wn2 + b2)  [N,64]
//   out= sigm(h2 @ Ws1 + mean_agg(h2) @ Wn1 + b1)  [N,128]
//
// History: R11 fp16 gather 336.7. R16 partition pack-u32 + NBLK256 + merged
//   wt: 317.1 (BEST). R17 full quant graft: 346.2 — gatherq<64> itself hit
//   44.7us / FETCH 135MB (byte-bound confirmed, 2nd time) but 3 extra
//   pipeline stages + 256 same-address LDS atomicMax/block (TRACKMAX) in
//   BOTH relu GEMMs ate the win.
// R18: quantize ONLY layer-1 (the 65us gather), minimal integration cost:
//   (a) no init kernel - wt_all zeroes the scale slot;
//   (b) TRACKMAX only on GEMM2, wave shfl-reduce -> 1 LDS atomic/wave ->
//       1 global atomic/block (was 256 same-address LDS atomics);
//   (c) ONE added launch (quant h2 -> u8, ~25MB streaming);
//   (d) layer-2/3 gathers + everything else byte-identical to R16.
// ---------------------------------------------------------------------------

typedef __attribute__((ext_vector_type(8))) _Float16 half8;
typedef __attribute__((ext_vector_type(4))) float floatx4;

#define NBUCKET 512
#define BUCKET_SHIFT 8   // 256 nodes per bucket; N = 131072 = 512*256

// ---- Pass A: per-block bucket histogram (LDS atomics only) ----
__global__ __launch_bounds__(256) void bucket_hist_kernel(
    const int* __restrict__ dst, int* __restrict__ bcnt, int E, int EPB, int nblk) {
    __shared__ int lh[NBUCKET];
    for (int i = threadIdx.x; i < NBUCKET; i += 256) lh[i] = 0;
    __syncthreads();
    int base = blockIdx.x * EPB;
    int end  = min(base + EPB, E);
    for (int i = base + threadIdx.x; i < end; i += 256)
        atomicAdd(&lh[dst[i] >> BUCKET_SHIFT], 1);
    __syncthreads();
    for (int i = threadIdx.x; i < NBUCKET; i += 256)
        bcnt[i * nblk + blockIdx.x] = lh[i];        // bucket-major
}

// ---- scan helpers ----
__global__ void scan1_kernel(const int* __restrict__ in, int* __restrict__ out,
                             int* __restrict__ bsum) {
    __shared__ int s[256];
    int i = blockIdx.x * 256 + threadIdx.x;
    int v = in[i];
    s[threadIdx.x] = v;
    __syncthreads();
    for (int off = 1; off < 256; off <<= 1) {
        int t = (threadIdx.x >= off) ? s[threadIdx.x - off] : 0;
        __syncthreads();
        s[threadIdx.x] += t;
        __syncthreads();
    }
    out[i] = s[threadIdx.x] - v;
    if (threadIdx.x == 255) bsum[blockIdx.x] = s[255];
}

__global__ void scan2_kernel(int* __restrict__ bsum, int NB) {
    extern __shared__ int s2[];
    int v = (threadIdx.x < NB) ? bsum[threadIdx.x] : 0;
    s2[threadIdx.x] = v;
    __syncthreads();
    for (int off = 1; off < NB; off <<= 1) {
        int t = (threadIdx.x >= off) ? s2[threadIdx.x - off] : 0;
        __syncthreads();
        s2[threadIdx.x] += t;
        __syncthreads();
    }
    if (threadIdx.x < NB) bsum[threadIdx.x] = s2[threadIdx.x] - v;
}

__global__ void scan3_kernel(int* __restrict__ out, const int* __restrict__ bsum) {
    int i = blockIdx.x * 256 + threadIdx.x;
    out[i] += bsum[blockIdx.x];
}

// ---- Pass C: partition edges into bucket segments (LDS cursors) ----
// Packed entry: (src << 8) | (dst & 255). src < 2^24, bucket-local dst 8b.
__global__ __launch_bounds__(256) void partition_kernel(
    const int* __restrict__ src, const int* __restrict__ dst,
    const int* __restrict__ bofs, int* __restrict__ part,
    int E, int EPB, int nblk) {
    __shared__ int cur[NBUCKET];
    for (int i = threadIdx.x; i < NBUCKET; i += 256)
        cur[i] = bofs[i * nblk + blockIdx.x];
    __syncthreads();
    int base = blockIdx.x * EPB;
    int end  = min(base + EPB, E);
    for (int i = base + threadIdx.x; i < end; i += 256) {
        int d = dst[i];
        int p = atomicAdd(&cur[d >> BUCKET_SHIFT], 1);
        part[p] = (src[i] << 8) | (d & 255);
    }
}

// ---- Pass D: per-bucket local CSR (row_ptr + csr_src), all LDS-local ----
__global__ __launch_bounds__(256) void local_csr_kernel(
    const int* __restrict__ bofs, const int* __restrict__ part,
    int* __restrict__ row_ptr, int* __restrict__ csr_src,
    int N, int E, int nblk) {
    __shared__ int cnt[256];
    __shared__ int offs[256];
    const int u      = blockIdx.x;
    const int node0  = u << BUCKET_SHIFT;
    const int bstart = bofs[(size_t)u * nblk];
    const int bend   = (u + 1 < gridDim.x) ? bofs[(size_t)(u + 1) * nblk] : E;

    cnt[threadIdx.x] = 0;
    __syncthreads();
    for (int i = bstart + threadIdx.x; i < bend; i += 256)
        atomicAdd(&cnt[part[i] & 255], 1);
    __syncthreads();

    int v = cnt[threadIdx.x];
    offs[threadIdx.x] = v;
    __syncthreads();
    for (int off = 1; off < 256; off <<= 1) {
        int t = (threadIdx.x >= off) ? offs[threadIdx.x - off] : 0;
        __syncthreads();
        offs[threadIdx.x] += t;
        __syncthreads();
    }
    int excl = offs[threadIdx.x] - v;
    int rbase = bstart + excl;
    if (node0 + threadIdx.x < N) row_ptr[node0 + threadIdx.x] = rbase;
    if (u == 0 && threadIdx.x == 0) row_ptr[N] = E;
    __syncthreads();
    cnt[threadIdx.x] = rbase;       // reuse as cursor
    __syncthreads();
    for (int i = bstart + threadIdx.x; i < bend; i += 256) {
        int e = part[i];
        int p = atomicAdd(&cnt[e & 255], 1);
        csr_src[p] = e >> 8;
    }
}

// ---- merged weight transpose+concat for all 3 layers (1 launch) ----
// Also zeroes the quant scale slot (replaces init kernel).
__global__ void wt_all_kernel(
    const float* __restrict__ Ws1, const float* __restrict__ Wn1, _Float16* __restrict__ Wt1,
    const float* __restrict__ Ws2, const float* __restrict__ Wn2, _Float16* __restrict__ Wt2,
    const float* __restrict__ Ws3, const float* __restrict__ Wn3, _Float16* __restrict__ Wt3,
    int* __restrict__ gmax) {
    int idx = blockIdx.x * 256 + threadIdx.x;
    if (idx == 0) gmax[0] = 0;
    const float *Ws, *Wn; _Float16* Wt; int CI, NOUT;
    if (idx < 16384)        { Ws = Ws1; Wn = Wn1; Wt = Wt1; CI = 64; NOUT = 128; }
    else if (idx < 20480)   { idx -= 16384; Ws = Ws2; Wn = Wn2; Wt = Wt2; CI = 32; NOUT = 64; }
    else if (idx < 21504)   { idx -= 20480; Ws = Ws3; Wn = Wn3; Wt = Wt3; CI = 16; NOUT = 32; }
    else return;
    int K = 2 * CI;
    int n = idx / K, k = idx - n * K;
    float v = (k < CI) ? Ws[(size_t)k * NOUT + n] : Wn[(size_t)(k - CI) * NOUT + n];
    Wt[n * K + k] = (_Float16)v;
}

// h0 = x @ W (16x16) + b, stored fp16
__global__ void lin16_kernel(const float* __restrict__ x, const float* __restrict__ W,
                             const float* __restrict__ b, _Float16* __restrict__ h, int N) {
    __shared__ float sW[256];
    __shared__ float sb[16];
    sW[threadIdx.x] = W[threadIdx.x];          // blockDim.x == 256
    if (threadIdx.x < 16) sb[threadIdx.x] = b[threadIdx.x];
    __syncthreads();
    int n = blockIdx.x * blockDim.x + threadIdx.x;
    if (n >= N) return;
    const float4* xr = (const float4*)(x + (size_t)n * 16);
    float4 x0 = xr[0], x1 = xr[1], x2 = xr[2], x3 = xr[3];
    float xi[16] = {x0.x, x0.y, x0.z, x0.w, x1.x, x1.y, x1.z, x1.w,
                    x2.x, x2.y, x2.z, x2.w, x3.x, x3.y, x3.z, x3.w};
    float o[16];
#pragma unroll
    for (int j = 0; j < 16; j++) o[j] = sb[j];
#pragma unroll
    for (int k = 0; k < 16; k++) {
        float xv = xi[k];
#pragma unroll
        for (int j = 0; j < 16; j++) o[j] += xv * sW[k * 16 + j];
    }
    half8 h0v, h1v;
#pragma unroll
    for (int j = 0; j < 8; j++) { h0v[j] = (_Float16)o[j]; h1v[j] = (_Float16)o[j + 8]; }
    half8* hr = (half8*)(h + (size_t)n * 16);
    hr[0] = h0v;
    hr[1] = h1v;
}

// agg[n][g*8..] = (1/max(deg,1)) * sum over CSR neighbors of h[src][g*8..]
// R11 form: 8-wide unrolled rounds + single masked tail round. (layers 2,3)
template <int C>
__global__ __launch_bounds__(256) void gather_kernel(
    const int* __restrict__ row_ptr, const int* __restrict__ csr_src,
    const _Float16* __restrict__ h, _Float16* __restrict__ agg, int N) {
    constexpr int GP = C / 8;
    int t = blockIdx.x * blockDim.x + threadIdx.x;
    int total = N * GP;
    if (t >= total) return;
    int n = t / GP;
    int g = t - n * GP;
    const int beg = row_ptr[n];
    const int end = row_ptr[n + 1];
    const size_t goff = (size_t)g * 8;

    float a0[8], a1[8];
#pragma unroll
    for (int i = 0; i < 8; i++) { a0[i] = 0.f; a1[i] = 0.f; }

    int j = beg;
    for (; j + 8 <= end; j += 8) {
        int i0 = csr_src[j + 0], i1 = csr_src[j + 1], i2 = csr_src[j + 2], i3 = csr_src[j + 3];
        int i4 = csr_src[j + 4], i5 = csr_src[j + 5], i6 = csr_src[j + 6], i7 = csr_src[j + 7];
        half8 v0 = *(const half8*)(h + (size_t)i0 * C + goff);
        half8 v1 = *(const half8*)(h + (size_t)i1 * C + goff);
        half8 v2 = *(const half8*)(h + (size_t)i2 * C + goff);
        half8 v3 = *(const half8*)(h + (size_t)i3 * C + goff);
        half8 v4 = *(const half8*)(h + (size_t)i4 * C + goff);
        half8 v5 = *(const half8*)(h + (size_t)i5 * C + goff);
        half8 v6 = *(const half8*)(h + (size_t)i6 * C + goff);
        half8 v7 = *(const half8*)(h + (size_t)i7 * C + goff);
#pragma unroll
        for (int i = 0; i < 8; i++) {
            a0[i] += ((float)v0[i] + (float)v2[i]) + ((float)v4[i] + (float)v6[i]);
            a1[i] += ((float)v1[i] + (float)v3[i]) + ((float)v5[i] + (float)v7[i]);
        }
    }
    if (j < end) {
        const int last = end - 1;
        int i0 = csr_src[j];
        int i1 = csr_src[min(j + 1, last)];
        int i2 = csr_src[min(j + 2, last)];
        int i3 = csr_src[min(j + 3, last)];
        int i4 = csr_src[min(j + 4, last)];
        int i5 = csr_src[min(j + 5, last)];
        int i6 = csr_src[min(j + 6, last)];
        int i7 = csr_src[min(j + 7, last)];
        half8 v0 = *(const half8*)(h + (size_t)i0 * C + goff);
        half8 v1 = *(const half8*)(h + (size_t)i1 * C + goff);
        half8 v2 = *(const half8*)(h + (size_t)i2 * C + goff);
        half8 v3 = *(const half8*)(h + (size_t)i3 * C + goff);
        half8 v4 = *(const half8*)(h + (size_t)i4 * C + goff);
        half8 v5 = *(const half8*)(h + (size_t)i5 * C + goff);
        half8 v6 = *(const half8*)(h + (size_t)i6 * C + goff);
        half8 v7 = *(const half8*)(h + (size_t)i7 * C + goff);
        float w1 = (j + 1 < end) ? 1.f : 0.f;
        float w2 = (j + 2 < end) ? 1.f : 0.f;
        float w3 = (j + 3 < end) ? 1.f : 0.f;
        float w4 = (j + 4 < end) ? 1.f : 0.f;
        float w5 = (j + 5 < end) ? 1.f : 0.f;
        float w6 = (j + 6 < end) ? 1.f : 0.f;
        float w7 = (j + 7 < end) ? 1.f : 0.f;
#pragma unroll
        for (int i = 0; i < 8; i++) {
            a0[i] += ((float)v0[i] + w2 * (float)v2[i]) + (w4 * (float)v4[i] + w6 * (float)v6[i]);
            a1[i] += (w1 * (float)v1[i] + w3 * (float)v3[i]) + (w5 * (float)v5[i] + w7 * (float)v7[i]);
        }
    }

    float inv = 1.0f / fmaxf((float)(end - beg), 1.0f);
    half8 r;
#pragma unroll
    for (int i = 0; i < 8; i++) r[i] = (_Float16)((a0[i] + a1[i]) * inv);
    *(half8*)(agg + (size_t)n * C + goff) = r;
}

// ---- quantize: q[i] = round(h[i] * 255/M), h >= 0 (relu) ----
__global__ __launch_bounds__(256) void quant_kernel(
    const _Float16* __restrict__ h, const int* __restrict__ maxbits,
    unsigned char* __restrict__ q, int total16) {
    int t = blockIdx.x * 256 + threadIdx.x;
    if (t >= total16) return;
    float M = __int_as_float(*maxbits);
    float inv = (M > 1e-20f) ? 255.0f / M : 0.0f;
    const half8* hp = (const half8*)(h + (size_t)t * 16);
    half8 v0 = hp[0], v1 = hp[1];
    unsigned int dw[4] = {0u, 0u, 0u, 0u};
#pragma unroll
    for (int i = 0; i < 8; i++) {
        unsigned int b = (unsigned int)((float)v0[i] * inv + 0.5f);
        if (b > 255u) b = 255u;
        dw[i >> 2] |= b << ((i & 3) * 8);
    }
#pragma unroll
    for (int i = 0; i < 8; i++) {
        unsigned int b = (unsigned int)((float)v1[i] * inv + 0.5f);
        if (b > 255u) b = 255u;
        dw[2 + (i >> 2)] |= b << ((i & 3) * 8);
    }
    uint4 o; o.x = dw[0]; o.y = dw[1]; o.z = dw[2]; o.w = dw[3];
    *(uint4*)(q + (size_t)t * 16) = o;
}

// int-accumulate helpers for u8 gather (exact: sum <= 255*deg << 2^31)
#define ACC4(d, o)                                 \
    { unsigned int _d = (d);                        \
      a[(o)]     += _d & 0xffu;                     \
      a[(o) + 1] += (_d >> 8) & 0xffu;              \
      a[(o) + 2] += (_d >> 16) & 0xffu;             \
      a[(o) + 3] += _d >> 24; }
#define ACC4W(d, w, o)                              \
    { unsigned int _d = (d); int _w = (w);          \
      a[(o)]     += _w * (int)(_d & 0xffu);         \
      a[(o) + 1] += _w * (int)((_d >> 8) & 0xffu);  \
      a[(o) + 2] += _w * (int)((_d >> 16) & 0xffu); \
      a[(o) + 3] += _w * (int)(_d >> 24); }

// ---- quantized gather (layer 1): agg = (M/255/deg) * int-sum of u8 rows ----
// Row = C bytes; GP = C/16 lanes/node, each lane one contiguous uint4 (16B).
template <int C>
__global__ __launch_bounds__(256) void gatherq_kernel(
    const int* __restrict__ row_ptr, const int* __restrict__ csr_src,
    const unsigned char* __restrict__ hq, const int* __restrict__ maxbits,
    _Float16* __restrict__ agg, int N) {
    constexpr int GP = C / 16;
    int t = blockIdx.x * 256 + threadIdx.x;
    if (t >= N * GP) return;
    int n = t / GP;
    int g = t & (GP - 1);
    const int beg = row_ptr[n];
    const int end = row_ptr[n + 1];
    const size_t goff = (size_t)g * 16;

    int a[16];
#pragma unroll
    for (int i = 0; i < 16; i++) a[i] = 0;

    int j = beg;
    for (; j + 4 <= end; j += 4) {
        int i0 = csr_src[j + 0], i1 = csr_src[j + 1];
        int i2 = csr_src[j + 2], i3 = csr_src[j + 3];
        uint4 q0 = *(const uint4*)(hq + (size_t)i0 * C + goff);
        uint4 q1 = *(const uint4*)(hq + (size_t)i1 * C + goff);
        uint4 q2 = *(const uint4*)(hq + (size_t)i2 * C + goff);
        uint4 q3 = *(const uint4*)(hq + (size_t)i3 * C + goff);
        ACC4(q0.x, 0) ACC4(q0.y, 4) ACC4(q0.z, 8) ACC4(q0.w, 12)
        ACC4(q1.x, 0) ACC4(q1.y, 4) ACC4(q1.z, 8) ACC4(q1.w, 12)
        ACC4(q2.x, 0) ACC4(q2.y, 4) ACC4(q2.z, 8) ACC4(q2.w, 12)
        ACC4(q3.x, 0) ACC4(q3.y, 4) ACC4(q3.z, 8) ACC4(q3.w, 12)
    }
    if (j < end) {
        const int last = end - 1;
        int i0 = csr_src[j];
        int i1 = csr_src[min(j + 1, last)];
        int i2 = csr_src[min(j + 2, last)];
        int i3 = csr_src[min(j + 3, last)];
        uint4 q0 = *(const uint4*)(hq + (size_t)i0 * C + goff);
        uint4 q1 = *(const uint4*)(hq + (size_t)i1 * C + goff);
        uint4 q2 = *(const uint4*)(hq + (size_t)i2 * C + goff);
        uint4 q3 = *(const uint4*)(hq + (size_t)i3 * C + goff);
        int w1 = (j + 1 < end) ? 1 : 0;
        int w2 = (j + 2 < end) ? 1 : 0;
        int w3 = (j + 3 < end) ? 1 : 0;
        ACC4(q0.x, 0) ACC4(q0.y, 4) ACC4(q0.z, 8) ACC4(q0.w, 12)
        ACC4W(q1.x, w1, 0) ACC4W(q1.y, w1, 4) ACC4W(q1.z, w1, 8) ACC4W(q1.w, w1, 12)
        ACC4W(q2.x, w2, 0) ACC4W(q2.y, w2, 4) ACC4W(q2.z, w2, 8) ACC4W(q2.w, w2, 12)
        ACC4W(q3.x, w3, 0) ACC4W(q3.y, w3, 4) ACC4W(q3.z, w3, 8) ACC4W(q3.w, w3, 12)
    }

    float M = __int_as_float(*maxbits);
    float sc = (M * (1.0f / 255.0f)) / fmaxf((float)(end - beg), 1.0f);
    half8 rl, rh;
#pragma unroll
    for (int i = 0; i < 8; i++) {
        rl[i] = (_Float16)((float)a[i] * sc);
        rh[i] = (_Float16)((float)a[i + 8] * sc);
    }
    half8* ap = (half8*)(agg + (size_t)n * C + goff);
    ap[0] = rl;
    ap[1] = rh;
}

// ---- MFMA GEMM: out = act([h | a] @ Wt^T + b) with Wt[n][K] fp16 ----
// TRACKMAX (GEMM2 only): per-thread max -> wave shfl reduce -> 1 LDS atomic
// per wave -> 1 global atomic per block. Valid since relu output >= 0.
template <int CI, int NOUT, int ACT, bool OUT_F16, bool TRACKMAX>
__global__ __launch_bounds__(256) void mfma_gemm_kernel(
    const _Float16* __restrict__ hbuf, const _Float16* __restrict__ abuf,
    const _Float16* __restrict__ Wt,   // [NOUT][K] fp16
    const float* __restrict__ bias, void* __restrict__ outp,
    int* __restrict__ maxbits, int N)
{
    constexpr int K   = 2 * CI;
    constexpr int KS  = K / 32;        // k-steps (4/2/1)
    constexpr int CT  = NOUT / 16;     // col tiles (8/4/2)
    constexpr int LDW = K + 8;         // padded LDS row (halves)
    __shared__ _Float16 Bt[NOUT * LDW];
    __shared__ int smax;

    const int tid = threadIdx.x;
    for (int idx = tid; idx < NOUT * (K / 8); idx += 256) {
        int n  = idx / (K / 8);
        int kq = idx - n * (K / 8);
        *(half8*)&Bt[n * LDW + kq * 8] = *(const half8*)(Wt + (size_t)n * K + kq * 8);
    }
    if (TRACKMAX && tid == 0) smax = 0;
    __syncthreads();

    const int wave = tid >> 6;
    const int lane = tid & 63;
    const int m    = lane & 15;
    const int quad = lane >> 4;
    const int row0 = blockIdx.x * 64 + wave * 16;
    const size_t row = (size_t)(row0 + m);

    floatx4 acc[CT];
#pragma unroll
    for (int c = 0; c < CT; c++) acc[c] = (floatx4){0.f, 0.f, 0.f, 0.f};

#pragma unroll
    for (int s = 0; s < KS; s++) {
        int k8 = s * 32 + quad * 8;
        const _Float16* Ap = (k8 < CI) ? (hbuf + row * CI + k8)
                                       : (abuf + row * CI + (k8 - CI));
        half8 a = *(const half8*)Ap;
#pragma unroll
        for (int c = 0; c < CT; c++) {
            half8 b = *(const half8*)&Bt[(c * 16 + m) * LDW + k8];
            acc[c] = __builtin_amdgcn_mfma_f32_16x16x32_f16(a, b, acc[c], 0, 0, 0);
        }
    }

    float tmax = 0.0f;
#pragma unroll
    for (int c = 0; c < CT; c++) {
        int col = c * 16 + m;
        float bv = bias[col];
#pragma unroll
        for (int j = 0; j < 4; j++) {
            int orow = row0 + quad * 4 + j;
            float v = acc[c][j] + bv;
            if (ACT == 0) v = fmaxf(v, 0.0f);
            else          v = 1.0f / (1.0f + __expf(-v));
            if (TRACKMAX) tmax = fmaxf(tmax, v);
            if (OUT_F16) ((_Float16*)outp)[(size_t)orow * NOUT + col] = (_Float16)v;
            else         ((float*)outp)[(size_t)orow * NOUT + col] = v;
        }
    }
    if (TRACKMAX) {
#pragma unroll
        for (int off = 32; off > 0; off >>= 1)
            tmax = fmaxf(tmax, __shfl_xor(tmax, off, 64));
        if (lane == 0) atomicMax(&smax, __float_as_int(tmax));
        __syncthreads();
        if (tid == 0) atomicMax(maxbits, smax);
    }
}

extern "C" void kernel_launch(void* const* d_in, const int* in_sizes, int n_in,
                              void* d_out, int out_size, void* d_ws, size_t ws_size,
                              hipStream_t stream) {
    const float* x     = (const float*)d_in[0];
    const int*   ei    = (const int*)d_in[1];
    // d_in[2]: batch (unused)
    const float* W_lin = (const float*)d_in[3];
    const float* b_lin = (const float*)d_in[4];
    const float* Ws3   = (const float*)d_in[5];
    const float* Wn3   = (const float*)d_in[6];
    const float* b3    = (const float*)d_in[7];
    const float* Ws2   = (const float*)d_in[8];
    const float* Wn2   = (const float*)d_in[9];
    const float* b2    = (const float*)d_in[10];
    const float* Ws1   = (const float*)d_in[11];
    const float* Wn1   = (const float*)d_in[12];
    const float* b1    = (const float*)d_in[13];
    float* out = (float*)d_out;

    const int N = in_sizes[0] / 16;
    const int E = in_sizes[1] / 2;
    const int* src = ei;
    const int* dst = ei + E;

    const int NBLK = 256;                       // partition blocks (~64B runs)
    const int EPB  = (E + NBLK - 1) / NBLK;
    const int M    = NBUCKET * NBLK;            // 131072 count entries
    const int NB2  = M / 256;                   // 512

    // Workspace (ints unless noted).
    int* wsi = (int*)d_ws;
    int* row_ptr = wsi;
    size_t B0 = ((size_t)(N + 1) + 3) & ~(size_t)3;
    int* bcnt = wsi + B0;
    int* bofs = bcnt + M;
    int* bsum = bofs + M;
    int* gmax = bsum + NB2;                     // [0] = max(h2)
    size_t C0 = (B0 + 2 * (size_t)M + (size_t)NB2 + 2 + 3) & ~(size_t)3;
    int* csr_src = wsi + C0;
    size_t P0 = (C0 + (size_t)E + 3) & ~(size_t)3;
    int* part = wsi + P0;                       // E packed u32; dead after local_csr
    size_t H0 = (P0 + (size_t)E + 3) & ~(size_t)3;
    _Float16* regA = (_Float16*)(wsi + H0);
    _Float16* regB = regA + (size_t)64 * N;
    _Float16* Wt1  = regB + (size_t)64 * N;     // 128*128 = 16384 halves
    _Float16* Wt2  = Wt1 + 16384;               // 64*64   = 4096
    _Float16* Wt3  = Wt2 + 4096;                // 32*32   = 1024

    _Float16* h0    = regA;
    _Float16* agg16 = regA + (size_t)16 * N;
    _Float16* h2    = regA;                    // after h0/agg16 dead
    _Float16* h3    = regB;
    _Float16* agg32 = regB + (size_t)32 * N;
    _Float16* agg64 = regB;                    // after h3/agg32 dead

    // u8 table for h2 overlays part's E-int space (8 MB, exact fit; part dead)
    unsigned char* h2q = (unsigned char*)part;  // N*64 bytes

    const int BLK = 256;

    // ---- weight transposes (1 merged launch; zeroes gmax) ----
    wt_all_kernel<<<(21504 + 255) / 256, 256, 0, stream>>>(
        Ws1, Wn1, Wt1, Ws2, Wn2, Wt2, Ws3, Wn3, Wt3, gmax);

    // ---- radix CSR build: zero global atomics ----
    bucket_hist_kernel<<<NBLK, 256, 0, stream>>>(dst, bcnt, E, EPB, NBLK);
    scan1_kernel<<<NB2, 256, 0, stream>>>(bcnt, bofs, bsum);
    scan2_kernel<<<1, NB2, NB2 * sizeof(int), stream>>>(bsum, NB2);
    scan3_kernel<<<NB2, 256, 0, stream>>>(bofs, bsum);
    partition_kernel<<<NBLK, 256, 0, stream>>>(src, dst, bofs, part, E, EPB, NBLK);
    local_csr_kernel<<<NBUCKET, 256, 0, stream>>>(bofs, part, row_ptr, csr_src, N, E, NBLK);

    // ---- h0 = x @ W_lin + b_lin (fp16 out) ----
    lin16_kernel<<<(N + BLK - 1) / BLK, BLK, 0, stream>>>(x, W_lin, b_lin, h0, N);

    // ---- block3: 16 -> 32, relu (fp16 gather) ----
    gather_kernel<16><<<((size_t)N * 2 + BLK - 1) / BLK, BLK, 0, stream>>>(row_ptr, csr_src, h0, agg16, N);
    mfma_gemm_kernel<16, 32, 0, true, false><<<N / 64, 256, 0, stream>>>(
        h0, agg16, Wt3, b3, h3, nullptr, N);

    // ---- block2: 32 -> 64, relu (fp16 gather; TRACKMAX on output h2) ----
    gather_kernel<32><<<((size_t)N * 4 + BLK - 1) / BLK, BLK, 0, stream>>>(row_ptr, csr_src, h3, agg32, N);
    mfma_gemm_kernel<32, 64, 0, true, true><<<N / 64, 256, 0, stream>>>(
        h3, agg32, Wt2, b2, h2, gmax, N);

    // ---- block1: 64 -> 128, sigmoid -> d_out fp32 (u8 quant gather) ----
    quant_kernel<<<(N * 4 + BLK - 1) / BLK, BLK, 0, stream>>>(h2, gmax, h2q, N * 4);
    gatherq_kernel<64><<<((size_t)N * 4 + BLK - 1) / BLK, BLK, 0, stream>>>(
        row_ptr, csr_src, h2q, gmax, agg64, N);
    mfma_gemm_kernel<64, 128, 1, false, false><<<N / 64, 256, 0, stream>>>(
        h2, agg64, Wt1, b1, out, nullptr, N);
}